// Round 1
// baseline (983.127 us; speedup 1.0000x reference)
//
#include <hip/hip_runtime.h>
#include <hip/hip_bf16.h>

// ---------------------------------------------------------------------------
// GCN 3-layer forward on MI355X.
// Pipeline per launch:
//   1. CSR build by dst: memset counts -> histogram -> exclusive scan -> scatter
//   2. L1: gemm_n128(x,W1) -> agg128(+b1, relu)
//   3. L2: gemm_n128(h1,W2) -> agg128(+b2, relu)
//   4. L3: gemm_n40(h2,W3) -> agg40_lsm(+b3, log_softmax) -> d_out
// Pull-based aggregation (CSR) avoids 474M fp32 atomics.
// ---------------------------------------------------------------------------

__device__ __forceinline__ void fma4(float4& c, float a, const float4& b) {
    c.x = fmaf(a, b.x, c.x);
    c.y = fmaf(a, b.y, c.y);
    c.z = fmaf(a, b.z, c.z);
    c.w = fmaf(a, b.w, c.w);
}

// ---------------- CSR build ----------------

__global__ void hist_kernel(const int* __restrict__ dst, int* __restrict__ counts, int E) {
    int i = blockIdx.x * blockDim.x + threadIdx.x;
    if (i < E) atomicAdd(&counts[dst[i]], 1);
}

// Single-block exclusive scan over counts[0..n) -> row_ptr[0..n], cursor copy.
__global__ void scan_kernel(const int* __restrict__ counts, int* __restrict__ row_ptr,
                            int* __restrict__ cursor, int n) {
    const int tid = threadIdx.x;
    const int lane = tid & 63, wv = tid >> 6;   // 16 waves of 64
    __shared__ int wsum[16];
    __shared__ int s_carry;
    if (tid == 0) s_carry = 0;
    __syncthreads();
    for (int base = 0; base < n; base += 4096) {
        int idx = base + tid * 4;
        int4 v = make_int4(0, 0, 0, 0);
        if (idx + 3 < n) {
            v = *(const int4*)(counts + idx);
        } else {
            if (idx     < n) v.x = counts[idx];
            if (idx + 1 < n) v.y = counts[idx + 1];
            if (idx + 2 < n) v.z = counts[idx + 2];
        }
        int s = v.x + v.y + v.z + v.w;
        int inc = s;
        #pragma unroll
        for (int off = 1; off < 64; off <<= 1) {
            int t = __shfl_up(inc, off, 64);
            if (lane >= off) inc += t;
        }
        if (lane == 63) wsum[wv] = inc;
        __syncthreads();
        int woff = 0, tile_total = 0;
        #pragma unroll
        for (int w = 0; w < 16; ++w) {
            int t = wsum[w];
            if (w < wv) woff += t;
            tile_total += t;
        }
        int carry = s_carry;
        int e0 = carry + woff + (inc - s);   // exclusive prefix at idx
        int e1 = e0 + v.x, e2 = e1 + v.y, e3 = e2 + v.z;
        if (idx     < n) { row_ptr[idx]     = e0; cursor[idx]     = e0; }
        if (idx + 1 < n) { row_ptr[idx + 1] = e1; cursor[idx + 1] = e1; }
        if (idx + 2 < n) { row_ptr[idx + 2] = e2; cursor[idx + 2] = e2; }
        if (idx + 3 < n) { row_ptr[idx + 3] = e3; cursor[idx + 3] = e3; }
        __syncthreads();
        if (tid == 0) s_carry = carry + tile_total;
        __syncthreads();
    }
    if (tid == 0) row_ptr[n] = s_carry;
}

__global__ void scatter_kernel(const int* __restrict__ src, const int* __restrict__ dst,
                               const float* __restrict__ val, int* __restrict__ cursor,
                               int* __restrict__ ssrc, float* __restrict__ sval, int E) {
    int i = blockIdx.x * blockDim.x + threadIdx.x;
    if (i < E) {
        int d = dst[i];
        int p = atomicAdd(&cursor[d], 1);
        ssrc[p] = src[i];
        sval[p] = val[i];
    }
}

// ---------------- GEMM, N=128 (layers 1 & 2) ----------------
// C[M x 128] = A[M x K] @ W[K x 128].  Block: 64 rows, 256 threads.
// Thread (rg=tid>>3, cg=tid&7) computes rows {2rg,2rg+1} x 16 cols
// (cols cg*4 + 32j + 0..3, j=0..3) -> conflict-free b128 LDS reads.

__global__ __launch_bounds__(256) void gemm_n128(const float* __restrict__ A,
                                                 const float* __restrict__ W,
                                                 float* __restrict__ C,
                                                 int M, int K) {
    constexpr int TM = 64, KB = 64;
    __shared__ __align__(16) float As[TM][KB + 4];
    __shared__ __align__(16) float Ws[KB][128];
    const int tid = threadIdx.x;
    const int cg = tid & 7;
    const int rg = tid >> 3;
    const int m0 = blockIdx.x * TM;
    const int r0 = 2 * rg, r1 = r0 + 1;

    float4 acc[2][4];
    #pragma unroll
    for (int i = 0; i < 2; ++i)
        #pragma unroll
        for (int j = 0; j < 4; ++j) acc[i][j] = make_float4(0.f, 0.f, 0.f, 0.f);

    for (int kb = 0; kb < K; kb += KB) {
        // A tile: 64x64 floats = 1024 float4, 4 per thread
        #pragma unroll
        for (int p = 0; p < 4; ++p) {
            int linear = tid + p * 256;
            int m = linear >> 4;          // 0..63
            int k4 = linear & 15;         // 0..15
            int gm = m0 + m;
            float4 v = make_float4(0.f, 0.f, 0.f, 0.f);
            if (gm < M) v = *(const float4*)(A + (size_t)gm * K + kb + k4 * 4);
            *(float4*)(&As[m][k4 * 4]) = v;
        }
        // W tile: 64x128 = 2048 float4, 8 per thread
        #pragma unroll
        for (int p = 0; p < 8; ++p) {
            int linear = tid + p * 256;
            int kk = linear >> 5;         // 0..63
            int c4 = linear & 31;
            *(float4*)(&Ws[kk][c4 * 4]) = *(const float4*)(W + (size_t)(kb + kk) * 128 + c4 * 4);
        }
        __syncthreads();
        #pragma unroll
        for (int kk = 0; kk < KB; ++kk) {
            float a0 = As[r0][kk], a1 = As[r1][kk];
            const float4* wrow = (const float4*)(&Ws[kk][0]);
            float4 b0 = wrow[cg], b1 = wrow[cg + 8], b2 = wrow[cg + 16], b3 = wrow[cg + 24];
            fma4(acc[0][0], a0, b0); fma4(acc[0][1], a0, b1);
            fma4(acc[0][2], a0, b2); fma4(acc[0][3], a0, b3);
            fma4(acc[1][0], a1, b0); fma4(acc[1][1], a1, b1);
            fma4(acc[1][2], a1, b2); fma4(acc[1][3], a1, b3);
        }
        __syncthreads();
    }
    #pragma unroll
    for (int i = 0; i < 2; ++i) {
        int gm = m0 + r0 + i;
        if (gm < M) {
            float4* crow = (float4*)(C + (size_t)gm * 128);
            crow[cg]      = acc[i][0];
            crow[cg + 8]  = acc[i][1];
            crow[cg + 16] = acc[i][2];
            crow[cg + 24] = acc[i][3];
        }
    }
}

// ---------------- GEMM, K=128, N=40 (layer 3) ----------------
// Block: 32 rows, 256 threads; thread (r=tid>>3, cg=tid&7) -> row r, cols cg*5..+4.

__global__ __launch_bounds__(256) void gemm_n40(const float* __restrict__ A,
                                                const float* __restrict__ W,
                                                float* __restrict__ C, int M) {
    constexpr int TM = 32;
    __shared__ __align__(16) float As[TM][128 + 4];
    __shared__ __align__(16) float Ws[128 * 40];
    const int tid = threadIdx.x;
    const int r = tid >> 3;
    const int cg = tid & 7;
    const int m0 = blockIdx.x * TM;

    for (int i = tid; i < 128 * 40; i += 256) Ws[i] = W[i];
    #pragma unroll
    for (int p = 0; p < 4; ++p) {
        int linear = tid + p * 256;
        int m = linear >> 5;          // 0..31
        int k4 = linear & 31;         // 0..31
        int gm = m0 + m;
        float4 v = make_float4(0.f, 0.f, 0.f, 0.f);
        if (gm < M) v = *(const float4*)(A + (size_t)gm * 128 + k4 * 4);
        *(float4*)(&As[m][k4 * 4]) = v;
    }
    __syncthreads();

    float acc[5] = {0.f, 0.f, 0.f, 0.f, 0.f};
    #pragma unroll 8
    for (int kk = 0; kk < 128; ++kk) {
        float a = As[r][kk];
        const float* wr = &Ws[kk * 40 + cg * 5];
        acc[0] = fmaf(a, wr[0], acc[0]);
        acc[1] = fmaf(a, wr[1], acc[1]);
        acc[2] = fmaf(a, wr[2], acc[2]);
        acc[3] = fmaf(a, wr[3], acc[3]);
        acc[4] = fmaf(a, wr[4], acc[4]);
    }
    int gm = m0 + r;
    if (gm < M) {
        float* crow = C + (size_t)gm * 40 + cg * 5;
        #pragma unroll
        for (int j = 0; j < 5; ++j) crow[j] = acc[j];
    }
}

// ---------------- Aggregation, F=128 (pull, CSR) ----------------
// 32-lane group per node; lane owns float4 (4 feats). Fuses +bias, relu.

__global__ __launch_bounds__(256) void agg128(const float* __restrict__ support,
                                              const int* __restrict__ row_ptr,
                                              const int* __restrict__ ssrc,
                                              const float* __restrict__ sval,
                                              const float* __restrict__ bias,
                                              float* __restrict__ out,
                                              int n, int do_relu) {
    int g = (blockIdx.x * blockDim.x + threadIdx.x) >> 5;
    int lane = threadIdx.x & 31;
    if (g >= n) return;
    int s = row_ptr[g], e = row_ptr[g + 1];
    float4 acc = make_float4(0.f, 0.f, 0.f, 0.f);
    const float4* sp = (const float4*)support;
    for (int i = s; i < e; ++i) {
        int src = ssrc[i];
        float v = sval[i];
        float4 t = sp[(size_t)src * 32 + lane];
        fma4(acc, v, t);
    }
    float4 b = ((const float4*)bias)[lane];
    acc.x += b.x; acc.y += b.y; acc.z += b.z; acc.w += b.w;
    if (do_relu) {
        acc.x = fmaxf(acc.x, 0.f); acc.y = fmaxf(acc.y, 0.f);
        acc.z = fmaxf(acc.z, 0.f); acc.w = fmaxf(acc.w, 0.f);
    }
    ((float4*)out)[(size_t)g * 32 + lane] = acc;
}

// ---------------- Aggregation F=40 + bias + log_softmax ----------------
// One 64-lane wave per node; lanes 0..39 carry features.

__global__ __launch_bounds__(256) void agg40_lsm(const float* __restrict__ support,
                                                 const int* __restrict__ row_ptr,
                                                 const int* __restrict__ ssrc,
                                                 const float* __restrict__ sval,
                                                 const float* __restrict__ bias,
                                                 float* __restrict__ out, int n) {
    int node = (blockIdx.x * blockDim.x + threadIdx.x) >> 6;
    int lane = threadIdx.x & 63;
    if (node >= n) return;
    int s = row_ptr[node], e = row_ptr[node + 1];
    float acc = 0.f;
    bool active = lane < 40;
    for (int i = s; i < e; ++i) {
        int src = ssrc[i];
        float v = sval[i];
        float t = active ? support[(size_t)src * 40 + lane] : 0.f;
        acc = fmaf(v, t, acc);
    }
    float val = active ? (acc + bias[lane]) : -INFINITY;
    float m = val;
    #pragma unroll
    for (int off = 32; off; off >>= 1) m = fmaxf(m, __shfl_xor(m, off, 64));
    float ex = active ? __expf(val - m) : 0.f;
    float ssum = ex;
    #pragma unroll
    for (int off = 32; off; off >>= 1) ssum += __shfl_xor(ssum, off, 64);
    if (active) out[(size_t)node * 40 + lane] = val - m - __logf(ssum);
}

// ---------------- launch ----------------

extern "C" void kernel_launch(void* const* d_in, const int* in_sizes, int n_in,
                              void* d_out, int out_size, void* d_ws, size_t ws_size,
                              hipStream_t stream) {
    const float* x         = (const float*)d_in[0];
    const int*   edge_src  = (const int*)d_in[1];
    const int*   edge_dst  = (const int*)d_in[2];
    const float* edge_vals = (const float*)d_in[3];
    const float* W1 = (const float*)d_in[4];
    const float* b1 = (const float*)d_in[5];
    const float* W2 = (const float*)d_in[6];
    const float* b2 = (const float*)d_in[7];
    const float* W3 = (const float*)d_in[8];
    const float* b3 = (const float*)d_in[9];

    const int N = in_sizes[0] / 256;   // 100000 nodes
    const int E = in_sizes[1];         // 1600000 edges

    char* p = (char*)d_ws;
    auto alloc = [&](size_t bytes) {
        char* r = p;
        p += (bytes + 255) & ~(size_t)255;
        return r;
    };
    float* bufA   = (float*)alloc((size_t)N * 128 * sizeof(float));  // support (51.2 MB)
    float* bufB   = (float*)alloc((size_t)N * 128 * sizeof(float));  // h       (51.2 MB)
    int*   ssrc   = (int*)  alloc((size_t)E * sizeof(int));
    float* sval   = (float*)alloc((size_t)E * sizeof(float));
    int*   row_ptr= (int*)  alloc((size_t)(N + 1) * sizeof(int));
    int*   cursor = (int*)  alloc((size_t)N * sizeof(int));
    int*   counts = (int*)  alloc((size_t)N * sizeof(int));

    // CSR build
    hipMemsetAsync(counts, 0, (size_t)N * sizeof(int), stream);
    hist_kernel<<<(E + 255) / 256, 256, 0, stream>>>(edge_dst, counts, E);
    scan_kernel<<<1, 1024, 0, stream>>>(counts, row_ptr, cursor, N);
    scatter_kernel<<<(E + 255) / 256, 256, 0, stream>>>(edge_src, edge_dst, edge_vals,
                                                        cursor, ssrc, sval, E);

    // Layer 1
    gemm_n128<<<(N + 63) / 64, 256, 0, stream>>>(x, W1, bufA, N, 256);
    agg128<<<((size_t)N * 32 + 255) / 256, 256, 0, stream>>>(bufA, row_ptr, ssrc, sval,
                                                             b1, bufB, N, 1);
    // Layer 2
    gemm_n128<<<(N + 63) / 64, 256, 0, stream>>>(bufB, W2, bufA, N, 128);
    agg128<<<((size_t)N * 32 + 255) / 256, 256, 0, stream>>>(bufA, row_ptr, ssrc, sval,
                                                             b2, bufB, N, 1);
    // Layer 3 + log_softmax
    gemm_n40<<<(N + 31) / 32, 256, 0, stream>>>(bufB, W3, bufA, N);
    agg40_lsm<<<((size_t)N * 64 + 255) / 256, 256, 0, stream>>>(bufA, row_ptr, ssrc, sval,
                                                                b3, (float*)d_out, N);
}

// Round 2
// 800.655 us; speedup vs baseline: 1.2279x; 1.2279x over previous
//
#include <hip/hip_runtime.h>
#include <hip/hip_bf16.h>

// ---------------------------------------------------------------------------
// GCN 3-layer forward on MI355X.
//   CSR build by dst -> (gemm + pull-aggregate) x3.
//   Layer 3 reordered: adj@(h2 W3) == (adj@h2) W3  => all aggs are F=128.
//   Gathered buffers (support1, support2, h2) stored bf16: halves gather bytes.
//   log_softmax fused into gemm_n40 epilogue.
// ---------------------------------------------------------------------------

__device__ __forceinline__ float bf2f(unsigned short u) {
    union { unsigned int i; float f; } cv; cv.i = ((unsigned int)u) << 16; return cv.f;
}
__device__ __forceinline__ unsigned short f2bf(float f) {
    union { float f; unsigned int i; } cv; cv.f = f;
    unsigned int lsb = (cv.i >> 16) & 1;
    cv.i += 0x7fffu + lsb;           // round-to-nearest-even
    return (unsigned short)(cv.i >> 16);
}

// ---------------- CSR build ----------------

__global__ void hist_kernel(const int* __restrict__ dst, int* __restrict__ counts, int E) {
    int i = blockIdx.x * blockDim.x + threadIdx.x;
    if (i < E) atomicAdd(&counts[dst[i]], 1);
}

__global__ void scan_kernel(const int* __restrict__ counts, int* __restrict__ row_ptr,
                            int* __restrict__ cursor, int n) {
    const int tid = threadIdx.x;
    const int lane = tid & 63, wv = tid >> 6;   // 16 waves of 64
    __shared__ int wsum[16];
    __shared__ int s_carry;
    if (tid == 0) s_carry = 0;
    __syncthreads();
    for (int base = 0; base < n; base += 4096) {
        int idx = base + tid * 4;
        int4 v = make_int4(0, 0, 0, 0);
        if (idx + 3 < n) {
            v = *(const int4*)(counts + idx);
        } else {
            if (idx     < n) v.x = counts[idx];
            if (idx + 1 < n) v.y = counts[idx + 1];
            if (idx + 2 < n) v.z = counts[idx + 2];
        }
        int s = v.x + v.y + v.z + v.w;
        int inc = s;
        #pragma unroll
        for (int off = 1; off < 64; off <<= 1) {
            int t = __shfl_up(inc, off, 64);
            if (lane >= off) inc += t;
        }
        if (lane == 63) wsum[wv] = inc;
        __syncthreads();
        int woff = 0, tile_total = 0;
        #pragma unroll
        for (int w = 0; w < 16; ++w) {
            int t = wsum[w];
            if (w < wv) woff += t;
            tile_total += t;
        }
        int carry = s_carry;
        int e0 = carry + woff + (inc - s);
        int e1 = e0 + v.x, e2 = e1 + v.y, e3 = e2 + v.z;
        if (idx     < n) { row_ptr[idx]     = e0; cursor[idx]     = e0; }
        if (idx + 1 < n) { row_ptr[idx + 1] = e1; cursor[idx + 1] = e1; }
        if (idx + 2 < n) { row_ptr[idx + 2] = e2; cursor[idx + 2] = e2; }
        if (idx + 3 < n) { row_ptr[idx + 3] = e3; cursor[idx + 3] = e3; }
        __syncthreads();
        if (tid == 0) s_carry = carry + tile_total;
        __syncthreads();
    }
    if (tid == 0) row_ptr[n] = s_carry;
}

// Pack (src, val) as int2 so the agg loop does one 8B load per edge.
__global__ void scatter_kernel(const int* __restrict__ src, const int* __restrict__ dst,
                               const float* __restrict__ val, int* __restrict__ cursor,
                               int2* __restrict__ epk, int E) {
    int i = blockIdx.x * blockDim.x + threadIdx.x;
    if (i < E) {
        int d = dst[i];
        int p = atomicAdd(&cursor[d], 1);
        epk[p] = make_int2(src[i], __float_as_int(val[i]));
    }
}

// ---------------- GEMM, N=128, bf16 output ----------------
// C[M x 128](bf16) = A[M x K](f32) @ W[K x 128](f32). Block: 64 rows, 256 thr.

__global__ __launch_bounds__(256) void gemm_n128_bf16o(const float* __restrict__ A,
                                                       const float* __restrict__ W,
                                                       unsigned short* __restrict__ C,
                                                       int M, int K) {
    constexpr int TM = 64, KB = 64;
    __shared__ __align__(16) float As[TM][KB + 4];
    __shared__ __align__(16) float Ws[KB][128];
    const int tid = threadIdx.x;
    const int cg = tid & 7;
    const int rg = tid >> 3;
    const int m0 = blockIdx.x * TM;
    const int r0 = 2 * rg, r1 = r0 + 1;

    float4 acc[2][4];
    #pragma unroll
    for (int i = 0; i < 2; ++i)
        #pragma unroll
        for (int j = 0; j < 4; ++j) acc[i][j] = make_float4(0.f, 0.f, 0.f, 0.f);

    for (int kb = 0; kb < K; kb += KB) {
        #pragma unroll
        for (int p = 0; p < 4; ++p) {
            int linear = tid + p * 256;
            int m = linear >> 4;
            int k4 = linear & 15;
            int gm = m0 + m;
            float4 v = make_float4(0.f, 0.f, 0.f, 0.f);
            if (gm < M) v = *(const float4*)(A + (size_t)gm * K + kb + k4 * 4);
            *(float4*)(&As[m][k4 * 4]) = v;
        }
        #pragma unroll
        for (int p = 0; p < 8; ++p) {
            int linear = tid + p * 256;
            int kk = linear >> 5;
            int c4 = linear & 31;
            *(float4*)(&Ws[kk][c4 * 4]) = *(const float4*)(W + (size_t)(kb + kk) * 128 + c4 * 4);
        }
        __syncthreads();
        #pragma unroll
        for (int kk = 0; kk < KB; ++kk) {
            float a0 = As[r0][kk], a1 = As[r1][kk];
            const float4* wrow = (const float4*)(&Ws[kk][0]);
            float4 b0 = wrow[cg], b1 = wrow[cg + 8], b2 = wrow[cg + 16], b3 = wrow[cg + 24];
            acc[0][0].x = fmaf(a0, b0.x, acc[0][0].x); acc[0][0].y = fmaf(a0, b0.y, acc[0][0].y);
            acc[0][0].z = fmaf(a0, b0.z, acc[0][0].z); acc[0][0].w = fmaf(a0, b0.w, acc[0][0].w);
            acc[0][1].x = fmaf(a0, b1.x, acc[0][1].x); acc[0][1].y = fmaf(a0, b1.y, acc[0][1].y);
            acc[0][1].z = fmaf(a0, b1.z, acc[0][1].z); acc[0][1].w = fmaf(a0, b1.w, acc[0][1].w);
            acc[0][2].x = fmaf(a0, b2.x, acc[0][2].x); acc[0][2].y = fmaf(a0, b2.y, acc[0][2].y);
            acc[0][2].z = fmaf(a0, b2.z, acc[0][2].z); acc[0][2].w = fmaf(a0, b2.w, acc[0][2].w);
            acc[0][3].x = fmaf(a0, b3.x, acc[0][3].x); acc[0][3].y = fmaf(a0, b3.y, acc[0][3].y);
            acc[0][3].z = fmaf(a0, b3.z, acc[0][3].z); acc[0][3].w = fmaf(a0, b3.w, acc[0][3].w);
            acc[1][0].x = fmaf(a1, b0.x, acc[1][0].x); acc[1][0].y = fmaf(a1, b0.y, acc[1][0].y);
            acc[1][0].z = fmaf(a1, b0.z, acc[1][0].z); acc[1][0].w = fmaf(a1, b0.w, acc[1][0].w);
            acc[1][1].x = fmaf(a1, b1.x, acc[1][1].x); acc[1][1].y = fmaf(a1, b1.y, acc[1][1].y);
            acc[1][1].z = fmaf(a1, b1.z, acc[1][1].z); acc[1][1].w = fmaf(a1, b1.w, acc[1][1].w);
            acc[1][2].x = fmaf(a1, b2.x, acc[1][2].x); acc[1][2].y = fmaf(a1, b2.y, acc[1][2].y);
            acc[1][2].z = fmaf(a1, b2.z, acc[1][2].z); acc[1][2].w = fmaf(a1, b2.w, acc[1][2].w);
            acc[1][3].x = fmaf(a1, b3.x, acc[1][3].x); acc[1][3].y = fmaf(a1, b3.y, acc[1][3].y);
            acc[1][3].z = fmaf(a1, b3.z, acc[1][3].z); acc[1][3].w = fmaf(a1, b3.w, acc[1][3].w);
        }
        __syncthreads();
    }
    #pragma unroll
    for (int i = 0; i < 2; ++i) {
        int gm = m0 + r0 + i;
        if (gm < M) {
            unsigned short* crow = C + (size_t)gm * 128;
            #pragma unroll
            for (int j = 0; j < 4; ++j) {
                float4 a = acc[i][j];
                ushort4 o;
                o.x = f2bf(a.x); o.y = f2bf(a.y); o.z = f2bf(a.z); o.w = f2bf(a.w);
                *(ushort4*)(crow + cg * 4 + 32 * j) = o;
            }
        }
    }
}

// ---------------- Aggregation, F=128, bf16 gather ----------------
// 32-lane group per node; lane owns 4 feats (ushort4 = 8B; 256B/edge coalesced).

template<bool BF16_OUT, bool RELU_BIAS>
__global__ __launch_bounds__(256) void agg128v(const ushort4* __restrict__ sup,
                                               const int* __restrict__ row_ptr,
                                               const int2* __restrict__ epk,
                                               const float* __restrict__ bias,
                                               void* __restrict__ out, int n) {
    int g = (blockIdx.x * blockDim.x + threadIdx.x) >> 5;
    int lane = threadIdx.x & 31;
    if (g >= n) return;
    int s = row_ptr[g], e = row_ptr[g + 1];
    float4 acc = make_float4(0.f, 0.f, 0.f, 0.f);
    int i = s;
    for (; i + 2 <= e; i += 2) {
        int2 e0 = epk[i], e1 = epk[i + 1];
        ushort4 t0 = sup[(size_t)e0.x * 32 + lane];
        ushort4 t1 = sup[(size_t)e1.x * 32 + lane];
        float v0 = __int_as_float(e0.y), v1 = __int_as_float(e1.y);
        acc.x = fmaf(v0, bf2f(t0.x), acc.x); acc.y = fmaf(v0, bf2f(t0.y), acc.y);
        acc.z = fmaf(v0, bf2f(t0.z), acc.z); acc.w = fmaf(v0, bf2f(t0.w), acc.w);
        acc.x = fmaf(v1, bf2f(t1.x), acc.x); acc.y = fmaf(v1, bf2f(t1.y), acc.y);
        acc.z = fmaf(v1, bf2f(t1.z), acc.z); acc.w = fmaf(v1, bf2f(t1.w), acc.w);
    }
    if (i < e) {
        int2 e0 = epk[i];
        ushort4 t0 = sup[(size_t)e0.x * 32 + lane];
        float v0 = __int_as_float(e0.y);
        acc.x = fmaf(v0, bf2f(t0.x), acc.x); acc.y = fmaf(v0, bf2f(t0.y), acc.y);
        acc.z = fmaf(v0, bf2f(t0.z), acc.z); acc.w = fmaf(v0, bf2f(t0.w), acc.w);
    }
    if (RELU_BIAS) {
        float4 b = ((const float4*)bias)[lane];
        acc.x = fmaxf(acc.x + b.x, 0.f);
        acc.y = fmaxf(acc.y + b.y, 0.f);
        acc.z = fmaxf(acc.z + b.z, 0.f);
        acc.w = fmaxf(acc.w + b.w, 0.f);
    }
    if (BF16_OUT) {
        ushort4 o;
        o.x = f2bf(acc.x); o.y = f2bf(acc.y); o.z = f2bf(acc.z); o.w = f2bf(acc.w);
        ((ushort4*)out)[(size_t)g * 32 + lane] = o;
    } else {
        ((float4*)out)[(size_t)g * 32 + lane] = acc;
    }
}

// ---------------- GEMM K=128 N=40 + bias + log_softmax ----------------
// Block: 32 rows, 256 thr; thread (r=tid>>3, cg=tid&7) -> row r, cols cg*5..+4.
// Row owned by 8 consecutive lanes -> shfl_xor(1,2,4) row reductions.

__global__ __launch_bounds__(256) void gemm_n40_lsm(const float* __restrict__ A,
                                                    const float* __restrict__ W,
                                                    const float* __restrict__ bias,
                                                    float* __restrict__ C, int M) {
    constexpr int TM = 32;
    __shared__ __align__(16) float As[TM][128 + 4];
    __shared__ __align__(16) float Ws[128 * 40];
    __shared__ float Bs[40];
    const int tid = threadIdx.x;
    const int r = tid >> 3;
    const int cg = tid & 7;
    const int m0 = blockIdx.x * TM;

    for (int i = tid; i < 128 * 40; i += 256) Ws[i] = W[i];
    if (tid < 40) Bs[tid] = bias[tid];
    #pragma unroll
    for (int p = 0; p < 4; ++p) {
        int linear = tid + p * 256;
        int m = linear >> 5;
        int k4 = linear & 31;
        int gm = m0 + m;
        float4 v = make_float4(0.f, 0.f, 0.f, 0.f);
        if (gm < M) v = *(const float4*)(A + (size_t)gm * 128 + k4 * 4);
        *(float4*)(&As[m][k4 * 4]) = v;
    }
    __syncthreads();

    float acc[5] = {0.f, 0.f, 0.f, 0.f, 0.f};
    #pragma unroll 8
    for (int kk = 0; kk < 128; ++kk) {
        float a = As[r][kk];
        const float* wr = &Ws[kk * 40 + cg * 5];
        acc[0] = fmaf(a, wr[0], acc[0]);
        acc[1] = fmaf(a, wr[1], acc[1]);
        acc[2] = fmaf(a, wr[2], acc[2]);
        acc[3] = fmaf(a, wr[3], acc[3]);
        acc[4] = fmaf(a, wr[4], acc[4]);
    }
    #pragma unroll
    for (int j = 0; j < 5; ++j) acc[j] += Bs[cg * 5 + j];

    // row max over the 8-lane group
    float m = acc[0];
    #pragma unroll
    for (int j = 1; j < 5; ++j) m = fmaxf(m, acc[j]);
    #pragma unroll
    for (int off = 1; off < 8; off <<= 1) m = fmaxf(m, __shfl_xor(m, off, 64));
    float ssum = 0.f;
    #pragma unroll
    for (int j = 0; j < 5; ++j) ssum += __expf(acc[j] - m);
    #pragma unroll
    for (int off = 1; off < 8; off <<= 1) ssum += __shfl_xor(ssum, off, 64);
    float lse = m + __logf(ssum);

    int gm = m0 + r;
    if (gm < M) {
        float* crow = C + (size_t)gm * 40 + cg * 5;
        #pragma unroll
        for (int j = 0; j < 5; ++j) crow[j] = acc[j] - lse;
    }
}

// ---------------- launch ----------------

extern "C" void kernel_launch(void* const* d_in, const int* in_sizes, int n_in,
                              void* d_out, int out_size, void* d_ws, size_t ws_size,
                              hipStream_t stream) {
    const float* x         = (const float*)d_in[0];
    const int*   edge_src  = (const int*)d_in[1];
    const int*   edge_dst  = (const int*)d_in[2];
    const float* edge_vals = (const float*)d_in[3];
    const float* W1 = (const float*)d_in[4];
    const float* b1 = (const float*)d_in[5];
    const float* W2 = (const float*)d_in[6];
    const float* b2 = (const float*)d_in[7];
    const float* W3 = (const float*)d_in[8];
    const float* b3 = (const float*)d_in[9];

    const int N = in_sizes[0] / 256;   // 100000
    const int E = in_sizes[1];         // 1600000

    char* p = (char*)d_ws;
    auto alloc = [&](size_t bytes) {
        char* r = p;
        p += (bytes + 255) & ~(size_t)255;
        return r;
    };
    unsigned short* sup  = (unsigned short*)alloc((size_t)N * 128 * 2);  // 25.6 MB (support1/2)
    float*          hf   = (float*)alloc((size_t)N * 128 * 4);           // 51.2 MB (h1, then h2agg)
    unsigned short* h2   = (unsigned short*)alloc((size_t)N * 128 * 2);  // 25.6 MB
    int2*  epk    = (int2*)alloc((size_t)E * sizeof(int2));              // 12.8 MB
    int*   row_ptr= (int*) alloc((size_t)(N + 1) * sizeof(int));
    int*   cursor = (int*) alloc((size_t)N * sizeof(int));
    int*   counts = (int*) alloc((size_t)N * sizeof(int));

    // CSR build
    hipMemsetAsync(counts, 0, (size_t)N * sizeof(int), stream);
    hist_kernel<<<(E + 255) / 256, 256, 0, stream>>>(edge_dst, counts, E);
    scan_kernel<<<1, 1024, 0, stream>>>(counts, row_ptr, cursor, N);
    scatter_kernel<<<(E + 255) / 256, 256, 0, stream>>>(edge_src, edge_dst, edge_vals,
                                                        cursor, epk, E);

    const int aggGrid = (int)(((size_t)N * 32 + 255) / 256);

    // Layer 1: sup = x@W1 (bf16) ; h1 = relu(agg(sup)+b1) (f32)
    gemm_n128_bf16o<<<(N + 63) / 64, 256, 0, stream>>>(x, W1, sup, N, 256);
    agg128v<false, true><<<aggGrid, 256, 0, stream>>>((const ushort4*)sup, row_ptr, epk,
                                                      b1, hf, N);
    // Layer 2: sup = h1@W2 (bf16) ; h2 = relu(agg(sup)+b2) (bf16)
    gemm_n128_bf16o<<<(N + 63) / 64, 256, 0, stream>>>(hf, W2, sup, N, 128);
    agg128v<true, true><<<aggGrid, 256, 0, stream>>>((const ushort4*)sup, row_ptr, epk,
                                                     b2, h2, N);
    // Layer 3 (reordered): h2agg = agg(h2) (f32) ; out = lsm(h2agg@W3 + b3)
    agg128v<false, false><<<aggGrid, 256, 0, stream>>>((const ushort4*)h2, row_ptr, epk,
                                                       nullptr, hf, N);
    gemm_n40_lsm<<<(N + 31) / 32, 256, 0, stream>>>(hf, W3, b3, (float*)d_out, N);
}

// Round 3
// 699.768 us; speedup vs baseline: 1.4049x; 1.1442x over previous
//
#include <hip/hip_runtime.h>
#include <hip/hip_bf16.h>

// ---------------------------------------------------------------------------
// GCN 3-layer forward on MI355X.
//   CSR build by dst -> (gemm + pull-aggregate) x3.
//   Layer 3 reordered: adj@(h2 W3) == (adj@h2) W3  => all aggs are F=128.
//   All intermediate node buffers bf16 (halves gather + GEMM-A traffic).
//   N=128 GEMMs use v_mfma_f32_16x16x32_bf16, 128x128 tile, BK=64,
//   XOR-swizzled LDS (conflict-free ds_read_b128 fragment loads).
//   log_softmax fused into gemm_n40 epilogue.
// ---------------------------------------------------------------------------

typedef __attribute__((ext_vector_type(8))) short short8;
typedef __attribute__((ext_vector_type(4))) float f32x4;

__device__ __forceinline__ float bf2f(unsigned short u) {
    union { unsigned int i; float f; } cv; cv.i = ((unsigned int)u) << 16; return cv.f;
}
__device__ __forceinline__ unsigned short f2bf(float f) {
    union { float f; unsigned int i; } cv; cv.f = f;
    unsigned int lsb = (cv.i >> 16) & 1;
    cv.i += 0x7fffu + lsb;           // round-to-nearest-even
    return (unsigned short)(cv.i >> 16);
}

// ---------------- CSR build ----------------

__global__ void hist_kernel(const int* __restrict__ dst, int* __restrict__ counts, int E) {
    int i = blockIdx.x * blockDim.x + threadIdx.x;
    if (i < E) atomicAdd(&counts[dst[i]], 1);
}

__global__ void scan_kernel(const int* __restrict__ counts, int* __restrict__ row_ptr,
                            int* __restrict__ cursor, int n) {
    const int tid = threadIdx.x;
    const int lane = tid & 63, wv = tid >> 6;   // 16 waves of 64
    __shared__ int wsum[16];
    __shared__ int s_carry;
    if (tid == 0) s_carry = 0;
    __syncthreads();
    for (int base = 0; base < n; base += 4096) {
        int idx = base + tid * 4;
        int4 v = make_int4(0, 0, 0, 0);
        if (idx + 3 < n) {
            v = *(const int4*)(counts + idx);
        } else {
            if (idx     < n) v.x = counts[idx];
            if (idx + 1 < n) v.y = counts[idx + 1];
            if (idx + 2 < n) v.z = counts[idx + 2];
        }
        int s = v.x + v.y + v.z + v.w;
        int inc = s;
        #pragma unroll
        for (int off = 1; off < 64; off <<= 1) {
            int t = __shfl_up(inc, off, 64);
            if (lane >= off) inc += t;
        }
        if (lane == 63) wsum[wv] = inc;
        __syncthreads();
        int woff = 0, tile_total = 0;
        #pragma unroll
        for (int w = 0; w < 16; ++w) {
            int t = wsum[w];
            if (w < wv) woff += t;
            tile_total += t;
        }
        int carry = s_carry;
        int e0 = carry + woff + (inc - s);
        int e1 = e0 + v.x, e2 = e1 + v.y, e3 = e2 + v.z;
        if (idx     < n) { row_ptr[idx]     = e0; cursor[idx]     = e0; }
        if (idx + 1 < n) { row_ptr[idx + 1] = e1; cursor[idx + 1] = e1; }
        if (idx + 2 < n) { row_ptr[idx + 2] = e2; cursor[idx + 2] = e2; }
        if (idx + 3 < n) { row_ptr[idx + 3] = e3; cursor[idx + 3] = e3; }
        __syncthreads();
        if (tid == 0) s_carry = carry + tile_total;
        __syncthreads();
    }
    if (tid == 0) row_ptr[n] = s_carry;
}

__global__ void scatter_kernel(const int* __restrict__ src, const int* __restrict__ dst,
                               const float* __restrict__ val, int* __restrict__ cursor,
                               int2* __restrict__ epk, int E) {
    int i = blockIdx.x * blockDim.x + threadIdx.x;
    if (i < E) {
        int d = dst[i];
        int p = atomicAdd(&cursor[d], 1);
        epk[p] = make_int2(src[i], __float_as_int(val[i]));
    }
}

// ---------------- W prep: W[K][128] f32 -> Wt[128][K] bf16 (n-major) -------

__global__ void prep_w(const float* __restrict__ W, unsigned short* __restrict__ Wt, int K) {
    int idx = blockIdx.x * blockDim.x + threadIdx.x;
    if (idx < 128 * K) {
        int n = idx / K, k = idx - n * K;
        Wt[idx] = f2bf(W[(size_t)k * 128 + n]);
    }
}

// ---------------- MFMA GEMM, N=128, bf16 in/out ----------------
// C[M x 128](bf16) = A[M x K] @ W[K x 128].  Block 128 rows, 256 thr (4 waves
// in 2x2), wave computes 64x64 via 4x4 tiles of 16x16x32 MFMA.
// LDS tiles [128][64] bf16, 16B chunks XOR-swizzled: chunk kg stored at
// kg ^ (row&7)  -> frag reads (stride 128 B) hit all 32 banks (2-way = free).

template<bool A_BF16>
__global__ __launch_bounds__(256) void gemm_mfma_n128(const void* __restrict__ Av,
                                                      const unsigned short* __restrict__ Bt,
                                                      unsigned short* __restrict__ C,
                                                      int M, int K) {
    __shared__ __align__(16) unsigned short As[128 * 64];
    __shared__ __align__(16) unsigned short Bs[128 * 64];
    const int tid = threadIdx.x;
    const int wave = tid >> 6, lane = tid & 63;
    const int wm = wave & 1, wn = wave >> 1;
    const int l15 = lane & 15, q = lane >> 4;
    const int m0 = blockIdx.x * 128;

    f32x4 acc[4][4];
    #pragma unroll
    for (int i = 0; i < 4; ++i)
        #pragma unroll
        for (int j = 0; j < 4; ++j)
            acc[i][j] = (f32x4)0.f;

    for (int kb = 0; kb < K; kb += 64) {
        // stage B: 128 rows (n) x 8 chunks of 8 bf16
        #pragma unroll
        for (int c = 0; c < 4; ++c) {
            int linear = tid + c * 256;           // 0..1023
            int n = linear >> 3, kg = linear & 7;
            short8 v = *(const short8*)(Bt + (size_t)n * K + kb + kg * 8);
            *(short8*)&Bs[n * 64 + ((kg ^ (n & 7)) * 8)] = v;
        }
        // stage A
        if (A_BF16) {
            const unsigned short* A = (const unsigned short*)Av;
            #pragma unroll
            for (int c = 0; c < 4; ++c) {
                int linear = tid + c * 256;
                int m = linear >> 3, kg = linear & 7;
                int gm = m0 + m;
                short8 v = 0;
                if (gm < M) v = *(const short8*)(A + (size_t)gm * K + kb + kg * 8);
                *(short8*)&As[m * 64 + ((kg ^ (m & 7)) * 8)] = v;
            }
        } else {
            const float* A = (const float*)Av;
            #pragma unroll
            for (int c = 0; c < 4; ++c) {
                int linear = tid + c * 256;
                int m = linear >> 3, kg = linear & 7;
                int gm = m0 + m;
                float4 v0 = make_float4(0.f, 0.f, 0.f, 0.f), v1 = v0;
                if (gm < M) {
                    const float* ap = A + (size_t)gm * K + kb + kg * 8;
                    v0 = *(const float4*)ap;
                    v1 = *(const float4*)(ap + 4);
                }
                short8 v;
                v[0] = (short)f2bf(v0.x); v[1] = (short)f2bf(v0.y);
                v[2] = (short)f2bf(v0.z); v[3] = (short)f2bf(v0.w);
                v[4] = (short)f2bf(v1.x); v[5] = (short)f2bf(v1.y);
                v[6] = (short)f2bf(v1.z); v[7] = (short)f2bf(v1.w);
                *(short8*)&As[m * 64 + ((kg ^ (m & 7)) * 8)] = v;
            }
        }
        __syncthreads();
        #pragma unroll
        for (int ks = 0; ks < 2; ++ks) {
            short8 af[4], bfr[4];
            int kg = ks * 4 + q;
            #pragma unroll
            for (int i = 0; i < 4; ++i) {
                int m = wm * 64 + i * 16 + l15;
                af[i] = *(const short8*)&As[m * 64 + ((kg ^ (m & 7)) * 8)];
            }
            #pragma unroll
            for (int j = 0; j < 4; ++j) {
                int n = wn * 64 + j * 16 + l15;
                bfr[j] = *(const short8*)&Bs[n * 64 + ((kg ^ (n & 7)) * 8)];
            }
            #pragma unroll
            for (int i = 0; i < 4; ++i)
                #pragma unroll
                for (int j = 0; j < 4; ++j)
                    acc[i][j] = __builtin_amdgcn_mfma_f32_16x16x32_bf16(af[i], bfr[j],
                                                                        acc[i][j], 0, 0, 0);
        }
        __syncthreads();
    }
    // epilogue: C/D mapping col=lane&15, row=q*4+r
    #pragma unroll
    for (int i = 0; i < 4; ++i) {
        int rbase = m0 + wm * 64 + i * 16 + q * 4;
        #pragma unroll
        for (int r = 0; r < 4; ++r) {
            int row = rbase + r;
            if (row < M) {
                #pragma unroll
                for (int j = 0; j < 4; ++j) {
                    int col = wn * 64 + j * 16 + l15;
                    C[(size_t)row * 128 + col] = f2bf(acc[i][j][r]);
                }
            }
        }
    }
}

// ---------------- Aggregation, F=128, bf16 gather ----------------
// 32-lane group per node; lane owns 4 feats (ushort4 = 8B; 256B/edge).

template<bool RELU_BIAS>
__global__ __launch_bounds__(256) void agg128v(const ushort4* __restrict__ sup,
                                               const int* __restrict__ row_ptr,
                                               const int2* __restrict__ epk,
                                               const float* __restrict__ bias,
                                               unsigned short* __restrict__ out, int n) {
    int g = (blockIdx.x * blockDim.x + threadIdx.x) >> 5;
    int lane = threadIdx.x & 31;
    if (g >= n) return;
    int s = row_ptr[g], e = row_ptr[g + 1];
    float4 acc = make_float4(0.f, 0.f, 0.f, 0.f);
    int i = s;
    for (; i + 2 <= e; i += 2) {
        int2 e0 = epk[i], e1 = epk[i + 1];
        ushort4 t0 = sup[(size_t)e0.x * 32 + lane];
        ushort4 t1 = sup[(size_t)e1.x * 32 + lane];
        float v0 = __int_as_float(e0.y), v1 = __int_as_float(e1.y);
        acc.x = fmaf(v0, bf2f(t0.x), acc.x); acc.y = fmaf(v0, bf2f(t0.y), acc.y);
        acc.z = fmaf(v0, bf2f(t0.z), acc.z); acc.w = fmaf(v0, bf2f(t0.w), acc.w);
        acc.x = fmaf(v1, bf2f(t1.x), acc.x); acc.y = fmaf(v1, bf2f(t1.y), acc.y);
        acc.z = fmaf(v1, bf2f(t1.z), acc.z); acc.w = fmaf(v1, bf2f(t1.w), acc.w);
    }
    if (i < e) {
        int2 e0 = epk[i];
        ushort4 t0 = sup[(size_t)e0.x * 32 + lane];
        float v0 = __int_as_float(e0.y);
        acc.x = fmaf(v0, bf2f(t0.x), acc.x); acc.y = fmaf(v0, bf2f(t0.y), acc.y);
        acc.z = fmaf(v0, bf2f(t0.z), acc.z); acc.w = fmaf(v0, bf2f(t0.w), acc.w);
    }
    if (RELU_BIAS) {
        float4 b = ((const float4*)bias)[lane];
        acc.x = fmaxf(acc.x + b.x, 0.f);
        acc.y = fmaxf(acc.y + b.y, 0.f);
        acc.z = fmaxf(acc.z + b.z, 0.f);
        acc.w = fmaxf(acc.w + b.w, 0.f);
    }
    ushort4 o;
    o.x = f2bf(acc.x); o.y = f2bf(acc.y); o.z = f2bf(acc.z); o.w = f2bf(acc.w);
    ((ushort4*)out)[(size_t)g * 32 + lane] = o;
}

// ---------------- GEMM K=128 N=40 + bias + log_softmax (bf16 A) ------------
// Block: 32 rows, 256 thr; thread (r=tid>>3, cg=tid&7) -> row r, cols cg*5..+4.

__global__ __launch_bounds__(256) void gemm_n40_lsm(const unsigned short* __restrict__ A,
                                                    const float* __restrict__ W,
                                                    const float* __restrict__ bias,
                                                    float* __restrict__ C, int M) {
    constexpr int TM = 32;
    __shared__ __align__(16) float As[TM][128 + 4];
    __shared__ __align__(16) float Ws[128 * 40];
    __shared__ float Bs[40];
    const int tid = threadIdx.x;
    const int r = tid >> 3;
    const int cg = tid & 7;
    const int m0 = blockIdx.x * TM;

    for (int i = tid; i < 128 * 40; i += 256) Ws[i] = W[i];
    if (tid < 40) Bs[tid] = bias[tid];
    #pragma unroll
    for (int p = 0; p < 4; ++p) {
        int linear = tid + p * 256;
        int m = linear >> 5;
        int k4 = linear & 31;
        int gm = m0 + m;
        float4 v = make_float4(0.f, 0.f, 0.f, 0.f);
        if (gm < M) {
            ushort4 u = *(const ushort4*)(A + (size_t)gm * 128 + k4 * 4);
            v = make_float4(bf2f(u.x), bf2f(u.y), bf2f(u.z), bf2f(u.w));
        }
        *(float4*)(&As[m][k4 * 4]) = v;
    }
    __syncthreads();

    float acc[5] = {0.f, 0.f, 0.f, 0.f, 0.f};
    #pragma unroll 8
    for (int kk = 0; kk < 128; ++kk) {
        float a = As[r][kk];
        const float* wr = &Ws[kk * 40 + cg * 5];
        acc[0] = fmaf(a, wr[0], acc[0]);
        acc[1] = fmaf(a, wr[1], acc[1]);
        acc[2] = fmaf(a, wr[2], acc[2]);
        acc[3] = fmaf(a, wr[3], acc[3]);
        acc[4] = fmaf(a, wr[4], acc[4]);
    }
    #pragma unroll
    for (int j = 0; j < 5; ++j) acc[j] += Bs[cg * 5 + j];

    float m = acc[0];
    #pragma unroll
    for (int j = 1; j < 5; ++j) m = fmaxf(m, acc[j]);
    #pragma unroll
    for (int off = 1; off < 8; off <<= 1) m = fmaxf(m, __shfl_xor(m, off, 64));
    float ssum = 0.f;
    #pragma unroll
    for (int j = 0; j < 5; ++j) ssum += __expf(acc[j] - m);
    #pragma unroll
    for (int off = 1; off < 8; off <<= 1) ssum += __shfl_xor(ssum, off, 64);
    float lse = m + __logf(ssum);

    int gm = m0 + r;
    if (gm < M) {
        float* crow = C + (size_t)gm * 40 + cg * 5;
        #pragma unroll
        for (int j = 0; j < 5; ++j) crow[j] = acc[j] - lse;
    }
}

// ---------------- launch ----------------

extern "C" void kernel_launch(void* const* d_in, const int* in_sizes, int n_in,
                              void* d_out, int out_size, void* d_ws, size_t ws_size,
                              hipStream_t stream) {
    const float* x         = (const float*)d_in[0];
    const int*   edge_src  = (const int*)d_in[1];
    const int*   edge_dst  = (const int*)d_in[2];
    const float* edge_vals = (const float*)d_in[3];
    const float* W1 = (const float*)d_in[4];
    const float* b1 = (const float*)d_in[5];
    const float* W2 = (const float*)d_in[6];
    const float* b2 = (const float*)d_in[7];
    const float* W3 = (const float*)d_in[8];
    const float* b3 = (const float*)d_in[9];

    const int N = in_sizes[0] / 256;   // 100000
    const int E = in_sizes[1];         // 1600000

    char* p = (char*)d_ws;
    auto alloc = [&](size_t bytes) {
        char* r = p;
        p += (bytes + 255) & ~(size_t)255;
        return r;
    };
    unsigned short* sup  = (unsigned short*)alloc((size_t)N * 128 * 2);  // 25.6 MB
    unsigned short* hbuf = (unsigned short*)alloc((size_t)N * 128 * 2);  // 25.6 MB
    unsigned short* Wt1  = (unsigned short*)alloc((size_t)128 * 256 * 2);
    unsigned short* Wt2  = (unsigned short*)alloc((size_t)128 * 128 * 2);
    int2*  epk    = (int2*)alloc((size_t)E * sizeof(int2));              // 12.8 MB
    int*   row_ptr= (int*) alloc((size_t)(N + 1) * sizeof(int));
    int*   cursor = (int*) alloc((size_t)N * sizeof(int));
    int*   counts = (int*) alloc((size_t)N * sizeof(int));

    // CSR build + W prep
    hipMemsetAsync(counts, 0, (size_t)N * sizeof(int), stream);
    hist_kernel<<<(E + 255) / 256, 256, 0, stream>>>(edge_dst, counts, E);
    prep_w<<<(128 * 256 + 255) / 256, 256, 0, stream>>>(W1, Wt1, 256);
    prep_w<<<(128 * 128 + 255) / 256, 256, 0, stream>>>(W2, Wt2, 128);
    scan_kernel<<<1, 1024, 0, stream>>>(counts, row_ptr, cursor, N);
    scatter_kernel<<<(E + 255) / 256, 256, 0, stream>>>(edge_src, edge_dst, edge_vals,
                                                        cursor, epk, E);

    const int aggGrid  = (int)(((size_t)N * 32 + 255) / 256);
    const int gemmGrid = (N + 127) / 128;

    // Layer 1: sup = x@W1 (bf16) ; h1 = relu(agg(sup)+b1) (bf16)
    gemm_mfma_n128<false><<<gemmGrid, 256, 0, stream>>>(x, Wt1, sup, N, 256);
    agg128v<true><<<aggGrid, 256, 0, stream>>>((const ushort4*)sup, row_ptr, epk, b1, hbuf, N);
    // Layer 2: sup = h1@W2 (bf16) ; h2 = relu(agg(sup)+b2) (bf16)
    gemm_mfma_n128<true><<<gemmGrid, 256, 0, stream>>>(hbuf, Wt2, sup, N, 128);
    agg128v<true><<<aggGrid, 256, 0, stream>>>((const ushort4*)sup, row_ptr, epk, b2, hbuf, N);
    // Layer 3 (reordered): h2agg = agg(h2) (bf16) ; out = lsm(h2agg@W3 + b3)
    agg128v<false><<<aggGrid, 256, 0, stream>>>((const ushort4*)hbuf, row_ptr, epk,
                                                nullptr, sup, N);
    gemm_n40_lsm<<<(N + 31) / 32, 256, 0, stream>>>(sup, W3, b3, (float*)d_out, N);
}